// Round 1
// baseline (550.102 us; speedup 1.0000x reference)
//
#include <hip/hip_runtime.h>

#define BB 8
#define TT 20
#define NSTK 1000
#define DINC 64
#define DDIM 64
#define KDIM 128     // DIN + D
#define THREADS 256

// LDS layout (floats):
//   wlds  [4][128][64] = 32768
//   xhlds [8][128]     = 1024   (xh: x part [0:64), h part [64:128))
//   glds  [8][256]     = 2048   (post-nonlinearity gates, [b][g*64+d])
//   wtlds [20][64]     = 1280
#define LDS_FLOATS (32768 + 1024 + 2048 + 1280)
#define LDS_BYTES (LDS_FLOATS * 4)

__device__ __forceinline__ float rl(float v, int lane) {
    return __int_as_float(__builtin_amdgcn_readlane(__float_as_int(v), lane));
}
__device__ __forceinline__ float sigmoid_f(float x) {
    return __builtin_amdgcn_rcpf(1.0f + __expf(-x));
}
__device__ __forceinline__ float tanh_f(float x) {
    // 1 - 2/(exp(2x)+1); saturates correctly for |x| large (inf -> 1, 0 -> -1)
    return 1.0f - 2.0f * __builtin_amdgcn_rcpf(__expf(2.0f * x) + 1.0f);
}

extern "C" __global__ void __launch_bounds__(THREADS, 1)
lstm_att_kernel(const float* __restrict__ x,
                const float* __restrict__ Wi, const float* __restrict__ bi,
                const float* __restrict__ Wo, const float* __restrict__ bo,
                const float* __restrict__ Wf, const float* __restrict__ bf,
                const float* __restrict__ Wc, const float* __restrict__ bc,
                const float* __restrict__ Wt,
                float* __restrict__ out)
{
    extern __shared__ __align__(16) float smem[];
    float* wlds  = smem;                      // 32768 floats
    float* xhlds = smem + 32768;              // 1024
    float* glds  = smem + 32768 + 1024;       // 2048
    float* wtlds = smem + 32768 + 1024 + 2048;// 1280

    const int n    = blockIdx.x;
    const int tid  = threadIdx.x;
    const int lane = tid & 63;

    // ---------------- init: stage weights, Wt, zero h ----------------
    {
        const float4* s0 = (const float4*)(Wi + (size_t)n * 8192);
        const float4* s1 = (const float4*)(Wo + (size_t)n * 8192);
        const float4* s2 = (const float4*)(Wf + (size_t)n * 8192);
        const float4* s3 = (const float4*)(Wc + (size_t)n * 8192);
        float4* dst = (float4*)wlds;
        #pragma unroll
        for (int j = 0; j < 8; ++j) {
            const int i = tid + j * THREADS;      // 0..2047
            dst[i]        = s0[i];
            dst[2048 + i] = s1[i];
            dst[4096 + i] = s2[i];
            dst[6144 + i] = s3[i];
        }
        #pragma unroll
        for (int j = 0; j < 5; ++j)
            wtlds[tid + j * THREADS] = Wt[(size_t)n * (TT * DDIM) + tid + j * THREADS];
        // zero h-part of xh
        const int bq = tid >> 5, jq = tid & 31;
        xhlds[bq * KDIM + DINC + 2 * jq]     = 0.0f;
        xhlds[bq * KDIM + DINC + 2 * jq + 1] = 0.0f;
    }

    // column-owner role: one output column (gate g, dim d) for all 8 batches
    const int g = tid >> 6;     // wave-uniform gate index
    const int d = tid & 63;
    const float bias = (g == 0 ? bi : g == 1 ? bo : g == 2 ? bf : bc)[n * DDIM + d];
    const float* wcol = wlds + g * (KDIM * DDIM) + d;   // + k*64

    // pair-owner role (state update): (b, d0), (b, d0+1)
    const int pb = tid >> 5;
    const int pd = (tid & 31) * 2;
    float creg0 = 0.0f, creg1 = 0.0f;       // LSTM cell state
    float oreg0 = 0.0f, oreg1 = 0.0f;       // online-softmax numerator
    float mreg = -3.0e38f, sreg = 0.0f;     // running max / denom

    for (int t = 0; t < TT; ++t) {
        // stage x[b,t,n,:] into xh (x part)
        {
            const int j = tid & 31;
            const float2 xv2 = *(const float2*)(x + ((size_t)(pb * TT + t) * NSTK + n) * DINC + 2 * j);
            *(float2*)(xhlds + pb * KDIM + 2 * j) = xv2;
        }
        __syncthreads();   // barrier A: xh (x-part from above, h-part from prev step) ready

        // distributed copy of xh into wave VGPRs: xv[2b+half] lane k holds xh[b][half*64+k]
        float xv[16];
        #pragma unroll
        for (int r = 0; r < 16; ++r) xv[r] = xhlds[r * 64 + lane];

        float acc[8];
        #pragma unroll
        for (int b = 0; b < 8; ++b) acc[b] = bias;

        // k-loop half 0 (x rows of W)
        #pragma unroll 8
        for (int kk = 0; kk < 64; ++kk) {
            const float w = wcol[kk * DDIM];
            #pragma unroll
            for (int b = 0; b < 8; ++b)
                acc[b] = fmaf(rl(xv[2 * b], kk), w, acc[b]);
        }
        // k-loop half 1 (h rows of W)
        #pragma unroll 8
        for (int kk = 0; kk < 64; ++kk) {
            const float w = wcol[(64 + kk) * DDIM];
            #pragma unroll
            for (int b = 0; b < 8; ++b)
                acc[b] = fmaf(rl(xv[2 * b + 1], kk), w, acc[b]);
        }

        // nonlinearity (wave-uniform branch: waves 0-2 sigmoid, wave 3 tanh) + gate exchange
        #pragma unroll
        for (int b = 0; b < 8; ++b) {
            const float v = (g == 3) ? tanh_f(acc[b]) : sigmoid_f(acc[b]);
            glds[b * 256 + tid] = v;
        }
        __syncthreads();   // barrier B: gates ready

        // state update for 2 (b,d) pairs
        const float2 ig = *(const float2*)(glds + pb * 256 +   0 + pd);
        const float2 og = *(const float2*)(glds + pb * 256 +  64 + pd);
        const float2 fg = *(const float2*)(glds + pb * 256 + 128 + pd);
        const float2 cg = *(const float2*)(glds + pb * 256 + 192 + pd);
        const float c0 = fmaf(fg.x, creg0, ig.x * cg.x);
        const float c1 = fmaf(fg.y, creg1, ig.y * cg.y);
        creg0 = c0; creg1 = c1;
        const float h0 = og.x * tanh_f(c0);
        const float h1 = og.y * tanh_f(c1);
        // h feeds next timestep's xh
        *(float2*)(xhlds + pb * KDIM + DINC + pd) = make_float2(h0, h1);

        // attention score: score[b][t] = sum_d h*Wt[n,t,d]  (reduce across the 32-lane b-group)
        float sp = fmaf(h0, wtlds[t * DDIM + pd], h1 * wtlds[t * DDIM + pd + 1]);
        #pragma unroll
        for (int m = 16; m >= 1; m >>= 1) sp += __shfl_xor(sp, m, 64);

        // online softmax update (uniform within b-group)
        const float mnew  = fmaxf(mreg, sp);
        const float scale = __expf(mreg - mnew);
        const float p     = __expf(sp - mnew);
        sreg  = fmaf(sreg, scale, p);
        oreg0 = fmaf(oreg0, scale, p * h0);
        oreg1 = fmaf(oreg1, scale, p * h1);
        mreg  = mnew;
        // no barrier needed here: next iter's x-writes touch only the x-part of xh,
        // and all xh/gate readers of this iter are already past barrier B.
    }

    // out[b][n][d] = o / s
    const float rs = __builtin_amdgcn_rcpf(sreg);
    *(float2*)(out + ((size_t)pb * NSTK + n) * DDIM + pd) = make_float2(oreg0 * rs, oreg1 * rs);
}

extern "C" void kernel_launch(void* const* d_in, const int* in_sizes, int n_in,
                              void* d_out, int out_size, void* d_ws, size_t ws_size,
                              hipStream_t stream) {
    const float* x  = (const float*)d_in[0];
    const float* Wi = (const float*)d_in[1];
    const float* bi = (const float*)d_in[2];
    const float* Wo = (const float*)d_in[3];
    const float* bo = (const float*)d_in[4];
    const float* Wf = (const float*)d_in[5];
    const float* bf = (const float*)d_in[6];
    const float* Wc = (const float*)d_in[7];
    const float* bc = (const float*)d_in[8];
    const float* Wt = (const float*)d_in[9];
    float* out = (float*)d_out;

    // 145 KiB dynamic LDS (> 64 KiB default cap): opt in. Host-side, capture-safe.
    hipFuncSetAttribute((const void*)lstm_att_kernel,
                        hipFuncAttributeMaxDynamicSharedMemorySize, LDS_BYTES);

    lstm_att_kernel<<<NSTK, THREADS, LDS_BYTES, stream>>>(
        x, Wi, bi, Wo, bo, Wf, bf, Wc, bc, Wt, out);
}

// Round 2
// 118.993 us; speedup vs baseline: 4.6230x; 4.6230x over previous
//
#include <hip/hip_runtime.h>

#define TT 20
#define NSTK 1000
#define THREADS 256

typedef float f32x4 __attribute__((ext_vector_type(4)));
typedef short bf16x8 __attribute__((ext_vector_type(8)));

__device__ __forceinline__ short f2bf(float f) {
    unsigned u = __float_as_uint(f);
    return (short)((u + 0x7fffu + ((u >> 16) & 1u)) >> 16);   // RNE
}
__device__ __forceinline__ float bf2f(short h) {
    return __uint_as_float(((unsigned)(unsigned short)h) << 16);
}
__device__ __forceinline__ float rcp_f(float x) { return __builtin_amdgcn_rcpf(x); }
__device__ __forceinline__ float sigmoid_f(float x) { return rcp_f(1.0f + __expf(-x)); }
__device__ __forceinline__ float tanh_f(float x) {
    return 1.0f - 2.0f * rcp_f(__expf(2.0f * x) + 1.0f);
}

// A-frag LDS layout (bf16): [kf 0..3][q=lane>>4 0..3][row 0..15][j 0..7]
//   k = kf*32 + q*8 + j ; rows 0..7 = batches, 8..15 zero padding.
// Same (q,j)->k convention used for A and B frags, so any bijective error in
// the true HW k-mapping cancels in the MFMA dot product.
#define AIDX(kf, q, row, j) ((((kf) * 4 + (q)) * 16 + (row)) * 8 + (j))

extern "C" __global__ void __launch_bounds__(THREADS, 2)
lstm_att_mfma(const float* __restrict__ x,
              const float* __restrict__ Wi, const float* __restrict__ bi,
              const float* __restrict__ Wo, const float* __restrict__ bo,
              const float* __restrict__ Wf, const float* __restrict__ bf_,
              const float* __restrict__ Wc, const float* __restrict__ bc,
              const float* __restrict__ Wt,
              float* __restrict__ out)
{
    __shared__ __align__(16) float wbuf[8192];      // 32 KB: W staging (init only)
    __shared__ __align__(16) short ahi[2048];       // 4 KB: xh hi bf16, frag layout
    __shared__ __align__(16) short alo[2048];       // 4 KB: xh lo bf16
    __shared__ __align__(16) float wtlds[TT * 64];  // 5 KB
    __shared__ __align__(16) float sparts[32];      // cross-wave score partials

    const int n    = blockIdx.x;
    const int tid  = threadIdx.x;
    const int lane = tid & 63;
    const int w    = tid >> 6;                 // wave id 0..3
    const int q    = lane >> 4;                // frag k-group
    const int r16  = lane & 15;                // frag row/col index
    const int dcol = w * 16 + r16;             // this lane's d (0..63)
    const int g4   = (lane >> 4) * 4;          // batch base for C rows (lanes<32)

    // ---------------- init ----------------
    #pragma unroll
    for (int u = 0; u < 8; ++u) { ahi[tid + u * THREADS] = 0; alo[tid + u * THREADS] = 0; }
    #pragma unroll
    for (int u = 0; u < 5; ++u)
        wtlds[tid + u * THREADS] = Wt[(size_t)n * (TT * 64) + tid + u * THREADS];

    // persistent B-fragments: W[k][d] for gate g, cols dcol, hi/lo bf16
    bf16x8 bhi[4][4], blo[4][4];               // [gate][kf]
    {
        const float* Wg[4] = {Wi, Wo, Wf, Wc};
        #pragma unroll
        for (int g = 0; g < 4; ++g) {
            __syncthreads();                   // wbuf reuse guard
            const float4* src = (const float4*)(Wg[g] + (size_t)n * 8192);
            float4* dst = (float4*)wbuf;
            #pragma unroll
            for (int u = 0; u < 8; ++u) dst[tid + u * THREADS] = src[tid + u * THREADS];
            __syncthreads();
            #pragma unroll
            for (int kf = 0; kf < 4; ++kf) {
                #pragma unroll
                for (int j = 0; j < 8; ++j) {
                    const float v = wbuf[(kf * 32 + q * 8 + j) * 64 + dcol];
                    const short hb = f2bf(v);
                    bhi[g][kf][j] = hb;
                    blo[g][kf][j] = f2bf(v - bf2f(hb));
                }
            }
        }
    }
    float biasv[4];
    biasv[0] = bi[n * 64 + dcol];
    biasv[1] = bo[n * 64 + dcol];
    biasv[2] = bf_[n * 64 + dcol];
    biasv[3] = bc[n * 64 + dcol];

    // per-lane state: 4 batches (g4+r) at dim dcol  (valid for lane<32)
    float cst[4]  = {0.f, 0.f, 0.f, 0.f};
    float onum[4] = {0.f, 0.f, 0.f, 0.f};
    float mst[4]  = {-3.0e38f, -3.0e38f, -3.0e38f, -3.0e38f};
    float sst[4]  = {0.f, 0.f, 0.f, 0.f};
    float h[4]    = {0.f, 0.f, 0.f, 0.f};

    __syncthreads();   // h-part of ahi/alo (zeros) visible before first reads

    for (int t = 0; t < TT; ++t) {
        // ---- stage x[b,t,n,:] into frag-layout LDS (hi/lo bf16) ----
        {
            const int sb = tid >> 5, dx = (tid & 31) * 2;
            const float2 xv = *(const float2*)(x + ((size_t)(sb * TT + t) * NSTK + n) * 64 + dx);
            const int kf = dx >> 5, kk = dx & 31, sq = kk >> 3, sj = kk & 7;
            const short h0 = f2bf(xv.x), h1 = f2bf(xv.y);
            const short l0 = f2bf(xv.x - bf2f(h0)), l1 = f2bf(xv.y - bf2f(h1));
            const int base = AIDX(kf, sq, sb, sj);
            *(short2*)(ahi + base) = make_short2(h0, h1);
            *(short2*)(alo + base) = make_short2(l0, l1);
        }
        __syncthreads();   // barrier A: x (this t) + h (prev t) frags ready

        // ---- load A-fragments ----
        bf16x8 afh[4], afl[4];
        const int abase = AIDX(0, q, r16, 0);
        #pragma unroll
        for (int kf = 0; kf < 4; ++kf) {
            afh[kf] = *(const bf16x8*)(ahi + abase + kf * 512);
            afl[kf] = *(const bf16x8*)(alo + abase + kf * 512);
        }

        // ---- MFMA: preacts for all 4 gates at this wave's d-slice ----
        f32x4 acc[4];
        #pragma unroll
        for (int g = 0; g < 4; ++g)
            acc[g] = (f32x4){biasv[g], biasv[g], biasv[g], biasv[g]};
        #pragma unroll
        for (int kf = 0; kf < 4; ++kf) {
            #pragma unroll
            for (int g = 0; g < 4; ++g) {
                acc[g] = __builtin_amdgcn_mfma_f32_16x16x32_bf16(afh[kf], bhi[g][kf], acc[g], 0, 0, 0);
                acc[g] = __builtin_amdgcn_mfma_f32_16x16x32_bf16(afl[kf], bhi[g][kf], acc[g], 0, 0, 0);
                acc[g] = __builtin_amdgcn_mfma_f32_16x16x32_bf16(afh[kf], blo[g][kf], acc[g], 0, 0, 0);
            }
        }

        // ---- nonlinearity + state update + score partials (C rows 0..7 live in lanes<32) ----
        float sp[4];
        if (lane < 32) {
            const float wtv = wtlds[t * 64 + dcol];
            #pragma unroll
            for (int r = 0; r < 4; ++r) {
                const float ig = sigmoid_f(acc[0][r]);
                const float og = sigmoid_f(acc[1][r]);
                const float fg = sigmoid_f(acc[2][r]);
                const float cg = tanh_f(acc[3][r]);
                const float cn = fmaf(fg, cst[r], ig * cg);
                cst[r] = cn;
                h[r] = og * tanh_f(cn);
                sp[r] = h[r] * wtv;
            }
            // reduce score over this wave's 16 d's (stays within 16-lane group)
            #pragma unroll
            for (int r = 0; r < 4; ++r) {
                #pragma unroll
                for (int mk = 8; mk >= 1; mk >>= 1)
                    sp[r] += __shfl_xor(sp[r], mk, 64);
            }
            if (r16 == 0)
                *(float4*)(sparts + w * 8 + g4) = make_float4(sp[0], sp[1], sp[2], sp[3]);
        }
        __syncthreads();   // barrier B: score partials ready; all A-frag reads done

        if (lane < 32) {
            const int kfh = 2 + (dcol >> 5), kkh = dcol & 31;
            const int qh = kkh >> 3, jh = kkh & 7;
            #pragma unroll
            for (int r = 0; r < 4; ++r) {
                // combine cross-wave score, online softmax
                const float sc = sparts[g4 + r] + sparts[8 + g4 + r] +
                                 sparts[16 + g4 + r] + sparts[24 + g4 + r];
                const float mn = fmaxf(mst[r], sc);
                const float scale = __expf(mst[r] - mn);
                const float p = __expf(sc - mn);
                sst[r]  = fmaf(sst[r], scale, p);
                onum[r] = fmaf(onum[r], scale, p * h[r]);
                mst[r]  = mn;
                // h -> next step's A-frag (hi/lo bf16), safe: all reads done at barrier B
                const short hh = f2bf(h[r]);
                const short hl = f2bf(h[r] - bf2f(hh));
                ahi[AIDX(kfh, qh, g4 + r, jh)] = hh;
                alo[AIDX(kfh, qh, g4 + r, jh)] = hl;
            }
        }
    }

    // ---- output: out[b][n][d] = onum / s ----
    if (lane < 32) {
        #pragma unroll
        for (int r = 0; r < 4; ++r)
            out[((size_t)(g4 + r) * NSTK + n) * 64 + dcol] = onum[r] * rcp_f(sst[r]);
    }
}

extern "C" void kernel_launch(void* const* d_in, const int* in_sizes, int n_in,
                              void* d_out, int out_size, void* d_ws, size_t ws_size,
                              hipStream_t stream) {
    const float* x  = (const float*)d_in[0];
    const float* Wi = (const float*)d_in[1];
    const float* bi = (const float*)d_in[2];
    const float* Wo = (const float*)d_in[3];
    const float* bo = (const float*)d_in[4];
    const float* Wf = (const float*)d_in[5];
    const float* bf = (const float*)d_in[6];
    const float* Wc = (const float*)d_in[7];
    const float* bc = (const float*)d_in[8];
    const float* Wt = (const float*)d_in[9];
    float* out = (float*)d_out;

    lstm_att_mfma<<<NSTK, THREADS, 0, stream>>>(
        x, Wi, bi, Wo, bo, Wf, bf, Wc, bc, Wt, out);
}